// Round 2
// baseline (5888.558 us; speedup 1.0000x reference)
//
#include <hip/hip_runtime.h>
#include <cstdint>
#include <cstddef>

typedef unsigned char  u8;
typedef unsigned short u16;
typedef unsigned int   u32;

typedef __attribute__((ext_vector_type(8))) short s16x8;
typedef __attribute__((ext_vector_type(4))) short s16x4;
typedef __attribute__((ext_vector_type(4))) float f32x4;

#define NWG 2048   // 262144 / 128

// ---------------- workspace layout (bytes), total ~16.7 MB ----------------
static const size_t PA_OFF   = 0;            // f32 [512][4096] sums
static const size_t PB_OFF   = 8388608;      // f32 [512][4096] sumsq
static const size_t MU_OFF   = 16777216;     // f32 [512]
static const size_t RSTD_OFF = 16779264;     // f32 [512]
static const size_t B1E_OFF  = 16781312;     // f32 [256]
static const size_t WEMB_OFF = 16782336;     // bf16 [3][256][32]
static const size_t WQ_OFF   = 16831488;     // bf16 [256][256]
static const size_t WK_OFF   = 16962560;     // bf16 [256][256]
static const size_t WV_OFF   = 17093632;     // bf16 [256][256]
static const size_t W2_OFF   = 17224704;     // bf16 [128][256]
static const size_t W1S_OFF  = 17290240;     // bf16 [256][512] BN-folded
// end = 17552384

__device__ __forceinline__ u16 f2bf(float f) {
  u32 u = __builtin_bit_cast(u32, f);
  u += 0x7FFFu + ((u >> 16) & 1u);     // RNE
  return (u16)(u >> 16);
}
__device__ __forceinline__ float bf2f(u16 h) {
  u32 u = ((u32)h) << 16;
  return __builtin_bit_cast(float, u);
}

// ---------------- K0: convert weights to bf16 ----------------
__global__ void k0_convert(const float* __restrict__ We,  const float* __restrict__ Wk1,
                           const float* __restrict__ Wk2, const float* __restrict__ Wq,
                           const float* __restrict__ Wk,  const float* __restrict__ Wv,
                           const float* __restrict__ W2,
                           u16* __restrict__ wEmb, u16* __restrict__ wQ, u16* __restrict__ wK,
                           u16* __restrict__ wV,  u16* __restrict__ wW2)
{
  int i = blockIdx.x * 256 + threadIdx.x;
  if (i < 3*256*32) {                       // padded embeds [agent][h][32]
    int which = i >> 13, rem = i & 8191, h = rem >> 5, c = rem & 31;
    const float* W = (which == 0) ? We : (which == 1) ? Wk1 : Wk2;
    wEmb[i] = (c < 13) ? f2bf(W[h*13 + c]) : (u16)0;
  } else if (i < 3*256*32 + 3*65536) {      // Wq, Wk, Wv
    int j = i - 3*256*32, which = j >> 16, rem = j & 65535;
    const float* W = (which == 0) ? Wq : (which == 1) ? Wk : Wv;
    u16* D = (which == 0) ? wQ : (which == 1) ? wK : wV;
    D[rem] = f2bf(W[rem]);
  } else {                                  // W2
    int j = i - (3*256*32 + 3*65536);
    if (j < 32768) wW2[j] = f2bf(W2[j]);
  }
}

// ----- helpers: xbuf is [128 rows][1024 B], XOR-swizzled by (row&7)<<4 -----
template<int NKS>
__device__ __forceinline__ void load_bfrags(const u8* __restrict__ xbuf, int cl, int colbase,
                                            int hi, s16x8* bk)
{
  #pragma unroll
  for (int ks = 0; ks < NKS; ++ks)
    bk[ks] = *(const s16x8*)(xbuf + ((cl*1024 + colbase + ks*64 + hi*16) ^ ((cl & 7) << 4)));
}

template<int NKS, int NM>
__device__ __forceinline__ void wgemm(const u16* __restrict__ W, const s16x8* bk,
                                      int lr, int hi, f32x4* acc)
{
  #pragma unroll
  for (int ks = 0; ks < NKS; ++ks) {
    #pragma unroll
    for (int m = 0; m < NM; ++m) {
      const s16x8 a = *(const s16x8*)(W + (m*16 + lr)*(NKS*32) + ks*32 + hi*8);
      acc[m] = __builtin_amdgcn_mfma_f32_16x16x32_bf16(a, bk[ks], acc[m], 0, 0, 0);
    }
  }
}

// streaming K-score GEMM: dot with qacc, no materialized accumulator array
__device__ __forceinline__ float wdot(const u16* __restrict__ W, const s16x8* bk,
                                      int lr, int hi, const f32x4* q)
{
  float sp = 0.f;
  #pragma unroll
  for (int m = 0; m < 16; ++m) {
    f32x4 k4 = {0.f, 0.f, 0.f, 0.f};
    #pragma unroll
    for (int ks = 0; ks < 8; ++ks) {
      const s16x8 a = *(const s16x8*)(W + (m*16 + lr)*256 + ks*32 + hi*8);
      k4 = __builtin_amdgcn_mfma_f32_16x16x32_bf16(a, bk[ks], k4, 0, 0, 0);
    }
    sp += q[m][0]*k4[0] + q[m][1]*k4[1] + q[m][2]*k4[2] + q[m][3]*k4[3];
  }
  return sp;
}

// streaming V2 GEMM with bias+leaky and softmax combine into vacc
__device__ __forceinline__ void v2_combine(const u16* __restrict__ W, const s16x8* bk,
                                           int lr, int hi, const float* __restrict__ bv,
                                           float w1, float w2, f32x4* vacc)
{
  #pragma unroll
  for (int m = 0; m < 16; ++m) {
    f32x4 v4 = {0.f, 0.f, 0.f, 0.f};
    #pragma unroll
    for (int ks = 0; ks < 8; ++ks) {
      const s16x8 a = *(const s16x8*)(W + (m*16 + lr)*256 + ks*32 + hi*8);
      v4 = __builtin_amdgcn_mfma_f32_16x16x32_bf16(a, bk[ks], v4, 0, 0, 0);
    }
    f32x4 bb = ((const f32x4*)bv)[m*4 + hi];
    #pragma unroll
    for (int r = 0; r < 4; ++r) {
      float v = v4[r] + bb[r];
      v = (v > 0.f) ? v : 0.01f*v;
      vacc[m][r] = w1*vacc[m][r] + w2*v;
    }
  }
}

__device__ __forceinline__ void egemm(const u16* __restrict__ Wj, s16x8 b,
                                      int lr, int hi, f32x4* acc)
{
  #pragma unroll
  for (int m = 0; m < 16; ++m) {
    const s16x8 a = *(const s16x8*)(Wj + (m*16 + lr)*32 + hi*8);
    acc[m] = __builtin_amdgcn_mfma_f32_16x16x32_bf16(a, b, acc[m], 0, 0, 0);
  }
}

template<bool HASB, bool RELU, int NM>
__device__ __forceinline__ void store_half(u8* __restrict__ xbuf, int colbase, const f32x4* acc,
                                           const float* __restrict__ bias, int cl, int hi)
{
  #pragma unroll
  for (int m = 0; m < NM; ++m) {
    f32x4 bb = {0.f, 0.f, 0.f, 0.f};
    if (HASB) bb = ((const f32x4*)bias)[m*4 + hi];
    s16x4 p;
    #pragma unroll
    for (int r = 0; r < 4; ++r) {
      float v = acc[m][r] + bb[r];
      if (RELU) v = (v > 0.f) ? v : 0.f;
      p[r] = (short)f2bf(v);
    }
    *(s16x4*)(xbuf + ((cl*1024 + colbase + m*32 + hi*8) ^ ((cl & 7) << 4))) = p;
  }
}

// ---- the shared attention tile: fills xbuf rows [e_q | atten] (bf16, swizzled) ----
__device__ __forceinline__ void attn_tile(
    const float* __restrict__ x, int rowbase,
    const u16* __restrict__ wEmb, const float* __restrict__ be,
    const float* __restrict__ bk1, const float* __restrict__ bk2,
    const u16* __restrict__ wQ, const u16* __restrict__ wK, const u16* __restrict__ wV,
    const float* __restrict__ bv,
    u8* __restrict__ xbuf, int cl, int lr, int hi)
{
  const f32x4 zero4 = {0.f, 0.f, 0.f, 0.f};

  // per-lane embed B-frags (K padded to 32; lane covers k = hi*8..hi*8+7)
  s16x8 bfr[3];
  {
    const float* xr = x + (size_t)(rowbase + cl)*39;
    #pragma unroll
    for (int a = 0; a < 3; ++a) {
      s16x8 v = {0,0,0,0,0,0,0,0};
      if (hi == 0) {
        #pragma unroll
        for (int e = 0; e < 8; ++e) v[e] = (short)f2bf(xr[12*a + e]);
      } else if (hi == 1) {
        #pragma unroll
        for (int e = 0; e < 4; ++e) v[e] = (short)f2bf(xr[12*a + 8 + e]);
        v[4] = (short)f2bf(xr[36 + a]);   // action column -> padded slot 12
      }
      bfr[a] = v;
    }
  }

  // ---- e_q -> cols 0..511 ----
  {
    f32x4 e[16];
    #pragma unroll
    for (int m = 0; m < 16; ++m) e[m] = zero4;
    egemm(wEmb, bfr[0], lr, hi, e);
    store_half<true, false, 16>(xbuf, 0, e, be, cl, hi);
  }
  __syncthreads();

  // ---- Q (reads e_q) ; e_k1 -> work (disjoint halves, no race) ----
  f32x4 qacc[16];
  #pragma unroll
  for (int m = 0; m < 16; ++m) qacc[m] = zero4;
  {
    s16x8 bk[8];
    load_bfrags<8>(xbuf, cl, 0, hi, bk);
    wgemm<8, 16>(wQ, bk, lr, hi, qacc);
  }
  {
    f32x4 e[16];
    #pragma unroll
    for (int m = 0; m < 16; ++m) e[m] = zero4;
    egemm(wEmb + 8192, bfr[1], lr, hi, e);
    store_half<true, false, 16>(xbuf, 512, e, bk1, cl, hi);
  }
  __syncthreads();

  // ---- K1 dot -> s1 ; V1 -> vacc (bias + leaky) ----
  float sc1;
  f32x4 vacc[16];
  #pragma unroll
  for (int m = 0; m < 16; ++m) vacc[m] = zero4;
  {
    s16x8 bk[8];
    load_bfrags<8>(xbuf, cl, 512, hi, bk);
    sc1 = wdot(wK, bk, lr, hi, qacc);
    sc1 += __shfl_xor(sc1, 16);
    sc1 += __shfl_xor(sc1, 32);
    wgemm<8, 16>(wV, bk, lr, hi, vacc);
  }
  #pragma unroll
  for (int m = 0; m < 16; ++m) {
    f32x4 bb = ((const f32x4*)bv)[m*4 + hi];
    #pragma unroll
    for (int r = 0; r < 4; ++r) {
      float v = vacc[m][r] + bb[r];
      vacc[m][r] = (v > 0.f) ? v : 0.01f*v;
    }
  }
  __syncthreads();

  // ---- e_k2 -> work ----
  {
    f32x4 e[16];
    #pragma unroll
    for (int m = 0; m < 16; ++m) e[m] = zero4;
    egemm(wEmb + 16384, bfr[2], lr, hi, e);
    store_half<true, false, 16>(xbuf, 512, e, bk2, cl, hi);
  }
  __syncthreads();

  // ---- K2 dot -> softmax -> V2 combine ----
  {
    s16x8 bk[8];
    load_bfrags<8>(xbuf, cl, 512, hi, bk);
    float sc2 = wdot(wK, bk, lr, hi, qacc);
    sc2 += __shfl_xor(sc2, 16);
    sc2 += __shfl_xor(sc2, 32);
    float w1 = 1.f / (1.f + __expf((sc2 - sc1) * 0.0625f));   // /sqrt(256)
    float w2 = 1.f - w1;
    v2_combine(wV, bk, lr, hi, bv, w1, w2, vacc);
  }
  __syncthreads();

  // ---- atten -> cols 512..1023 ----
  store_half<false, false, 16>(xbuf, 512, vacc, nullptr, cl, hi);
  __syncthreads();
}

// ---------------- K1: attention pass -> BN partial sums ----------------
__global__ __launch_bounds__(512, 2) void k1_attn(
    const float* __restrict__ x,
    const u16* __restrict__ wEmb, const float* __restrict__ be,
    const float* __restrict__ bk1, const float* __restrict__ bk2,
    const u16* __restrict__ wQ, const u16* __restrict__ wK, const u16* __restrict__ wV,
    const float* __restrict__ bv,
    float* __restrict__ pA, float* __restrict__ pB)
{
  __shared__ __align__(16) u8 xbuf[131072];
  const int t = threadIdx.x;
  const int wg = blockIdx.x;
  const int rowbase = wg * 128;
  const int lane = t & 63;
  const int wv_ = t >> 6;
  const int lr = lane & 15, hi = lane >> 4;
  const int cl = wv_*16 + lr;

  attn_tile(x, rowbase, wEmb, be, bk1, bk2, wQ, wK, wV, bv, xbuf, cl, lr, hi);

  // BN partials: thread handles feature pair (2fp, 2fp+1), row half rh
  const int fp = t & 255, rh = t >> 8;
  float s0 = 0.f, q0 = 0.f, s1 = 0.f, q1 = 0.f;
  for (int rr = 0; rr < 64; ++rr) {
    int r = rh*64 + rr;
    u32 v = *(const u32*)(xbuf + ((r*1024 + fp*4) ^ ((r & 7) << 4)));
    float a = bf2f((u16)(v & 0xFFFFu));
    float b = bf2f((u16)(v >> 16));
    s0 += a; q0 += a*a; s1 += b; q1 += b*b;
  }
  pA[(size_t)(2*fp)  *4096 + wg*2 + rh] = s0;
  pB[(size_t)(2*fp)  *4096 + wg*2 + rh] = q0;
  pA[(size_t)(2*fp+1)*4096 + wg*2 + rh] = s1;
  pB[(size_t)(2*fp+1)*4096 + wg*2 + rh] = q1;
}

// ---------------- K2: reduce BN partials -> mu, rstd ----------------
__global__ void k2_stats(const float* __restrict__ pA, const float* __restrict__ pB,
                         float* __restrict__ mu, float* __restrict__ rstd)
{
  int f = blockIdx.x, t = threadIdx.x;   // 512 blocks x 256 threads
  float s = 0.f, q = 0.f;
  #pragma unroll
  for (int k = 0; k < 16; ++k) {
    s += pA[(size_t)f*4096 + k*256 + t];
    q += pB[(size_t)f*4096 + k*256 + t];
  }
  #pragma unroll
  for (int off = 1; off < 64; off <<= 1) {
    s += __shfl_xor(s, off);
    q += __shfl_xor(q, off);
  }
  __shared__ float ls[4], lq[4];
  if ((t & 63) == 0) { ls[t >> 6] = s; lq[t >> 6] = q; }
  __syncthreads();
  if (t == 0) {
    float S = ls[0]+ls[1]+ls[2]+ls[3];
    float Q = lq[0]+lq[1]+lq[2]+lq[3];
    float m = S * (1.f/262144.f);
    float v = Q * (1.f/262144.f) - m*m;   // biased variance
    mu[f] = m;
    rstd[f] = 1.f / sqrtf(v + 1e-5f);
  }
}

// ---------------- K2b: fold BN into W1 ----------------
__global__ void k2b_fold(const float* __restrict__ W1, const float* __restrict__ b1,
                         const float* __restrict__ mu, const float* __restrict__ rstd,
                         u16* __restrict__ W1s, float* __restrict__ b1eff)
{
  int o = blockIdx.x, t = threadIdx.x;   // 256 blocks x 256 threads
  float local = 0.f;
  #pragma unroll
  for (int k = 0; k < 2; ++k) {
    int f = t + k*256;
    float w = W1[o*512 + f];
    float r = rstd[f];
    W1s[o*512 + f] = f2bf(w * r);
    local += w * r * mu[f];
  }
  #pragma unroll
  for (int off = 1; off < 64; off <<= 1) local += __shfl_xor(local, off);
  __shared__ float ls[4];
  if ((t & 63) == 0) ls[t >> 6] = local;
  __syncthreads();
  if (t == 0) b1eff[o] = b1[o] - (ls[0]+ls[1]+ls[2]+ls[3]);
}

// ---------------- K3: attention recompute + MLP head ----------------
__global__ __launch_bounds__(512, 2) void k3_mlp(
    const float* __restrict__ x,
    const u16* __restrict__ wEmb, const float* __restrict__ be,
    const float* __restrict__ bk1, const float* __restrict__ bk2,
    const u16* __restrict__ wQ, const u16* __restrict__ wK, const u16* __restrict__ wV,
    const float* __restrict__ bv,
    const u16* __restrict__ W1s, const float* __restrict__ b1eff,
    const u16* __restrict__ wW2, const float* __restrict__ b2,
    const float* __restrict__ W3, const float* __restrict__ b3,
    float* __restrict__ out)
{
  __shared__ __align__(16) u8 xbuf[131072];
  const int t = threadIdx.x;
  const int wg = blockIdx.x;
  const int rowbase = wg * 128;
  const int lane = t & 63;
  const int wv_ = t >> 6;
  const int lr = lane & 15, hi = lane >> 4;
  const int cl = wv_*16 + lr;
  const f32x4 zero4 = {0.f, 0.f, 0.f, 0.f};

  attn_tile(x, rowbase, wEmb, be, bk1, bk2, wQ, wK, wV, bv, xbuf, cl, lr, hi);

  // ---- GEMM1: h1 = relu(X @ W1s.T + b1eff), K = 512 (full rows) ----
  f32x4 acc[16];
  #pragma unroll
  for (int m = 0; m < 16; ++m) acc[m] = zero4;
  {
    s16x8 bk[16];
    load_bfrags<16>(xbuf, cl, 0, hi, bk);
    wgemm<16, 16>(W1s, bk, lr, hi, acc);
  }
  __syncthreads();                               // all X reads done
  store_half<true, true, 16>(xbuf, 0, acc, b1eff, cl, hi);   // h1 -> cols 0..511
  __syncthreads();

  // ---- GEMM2: h2 = relu(h1 @ W2.T + b2), K = 256 ----
  f32x4 acc2[8];
  #pragma unroll
  for (int m = 0; m < 8; ++m) acc2[m] = zero4;
  {
    s16x8 bk[8];
    load_bfrags<8>(xbuf, cl, 0, hi, bk);
    wgemm<8, 8>(wW2, bk, lr, hi, acc2);
  }
  __syncthreads();
  store_half<true, true, 8>(xbuf, 512, acc2, b2, cl, hi);    // h2 -> cols 512..767
  __syncthreads();

  // ---- out = h2 @ W3.T + b3 (one thread per row) ----
  if (t < 128) {
    float s = b3[0];
    #pragma unroll
    for (int jj = 0; jj < 16; ++jj) {
      const u32* v = (const u32*)(xbuf + ((t*1024 + 512 + jj*16) ^ ((t & 7) << 4)));
      #pragma unroll
      for (int q2 = 0; q2 < 4; ++q2) {
        u32 u = v[q2];
        s += bf2f((u16)(u & 0xFFFFu)) * W3[jj*8 + q2*2];
        s += bf2f((u16)(u >> 16))     * W3[jj*8 + q2*2 + 1];
      }
    }
    out[rowbase + t] = s;
  }
}

extern "C" void kernel_launch(void* const* d_in, const int* in_sizes, int n_in,
                              void* d_out, int out_size, void* d_ws, size_t ws_size,
                              hipStream_t stream)
{
  const float* x   = (const float*)d_in[0];
  const float* We  = (const float*)d_in[1];
  const float* be  = (const float*)d_in[2];
  const float* Wk1 = (const float*)d_in[3];
  const float* bk1 = (const float*)d_in[4];
  const float* Wk2 = (const float*)d_in[5];
  const float* bk2 = (const float*)d_in[6];
  const float* Wq  = (const float*)d_in[7];
  const float* Wk  = (const float*)d_in[8];
  const float* Wv  = (const float*)d_in[9];
  const float* bv  = (const float*)d_in[10];
  const float* W1  = (const float*)d_in[11];
  const float* b1  = (const float*)d_in[12];
  const float* W2  = (const float*)d_in[13];
  const float* b2  = (const float*)d_in[14];
  const float* W3  = (const float*)d_in[15];
  const float* b3  = (const float*)d_in[16];

  u8* ws = (u8*)d_ws;
  float* pA    = (float*)(ws + PA_OFF);
  float* pB    = (float*)(ws + PB_OFF);
  float* mu    = (float*)(ws + MU_OFF);
  float* rstd  = (float*)(ws + RSTD_OFF);
  float* b1eff = (float*)(ws + B1E_OFF);
  u16*   wEmb  = (u16*)(ws + WEMB_OFF);
  u16*   wQb   = (u16*)(ws + WQ_OFF);
  u16*   wKb   = (u16*)(ws + WK_OFF);
  u16*   wVb   = (u16*)(ws + WV_OFF);
  u16*   wW2   = (u16*)(ws + W2_OFF);
  u16*   wW1s  = (u16*)(ws + W1S_OFF);

  k0_convert<<<dim3(992), dim3(256), 0, stream>>>(We, Wk1, Wk2, Wq, Wk, Wv, W2,
                                                  wEmb, wQb, wKb, wVb, wW2);
  k1_attn<<<dim3(NWG), dim3(512), 0, stream>>>(x, wEmb, be, bk1, bk2, wQb, wKb, wVb, bv,
                                               pA, pB);
  k2_stats<<<dim3(512), dim3(256), 0, stream>>>(pA, pB, mu, rstd);
  k2b_fold<<<dim3(256), dim3(256), 0, stream>>>(W1, b1, mu, rstd, wW1s, b1eff);
  k3_mlp<<<dim3(NWG), dim3(512), 0, stream>>>(x, wEmb, be, bk1, bk2, wQb, wKb, wVb, bv,
                                              wW1s, b1eff, wW2, b2, W3, b3,
                                              (float*)d_out);
}

// Round 3
// 2179.357 us; speedup vs baseline: 2.7020x; 2.7020x over previous
//
#include <hip/hip_runtime.h>
#include <cstdint>
#include <cstddef>

typedef unsigned char  u8;
typedef unsigned short u16;
typedef unsigned int   u32;

typedef __attribute__((ext_vector_type(8))) short s16x8;
typedef __attribute__((ext_vector_type(4))) short s16x4;
typedef __attribute__((ext_vector_type(4))) float f32x4;

#define NWG 2048   // 262144 / 128

// ---------------- workspace layout (bytes), total ~16.7 MB ----------------
static const size_t PA_OFF   = 0;            // f32 [512][4096] sums
static const size_t PB_OFF   = 8388608;      // f32 [512][4096] sumsq
static const size_t MU_OFF   = 16777216;     // f32 [512]
static const size_t RSTD_OFF = 16779264;     // f32 [512]
static const size_t B1E_OFF  = 16781312;     // f32 [256]
static const size_t WEMB_OFF = 16782336;     // bf16 [3][256][32]
static const size_t WU_OFF   = 16831488;     // bf16 [256][256]  Wu = Wq^T Wk fold
static const size_t WV_OFF   = 16962560;     // bf16 [256][256]
static const size_t W2_OFF   = 17093632;     // bf16 [128][256]
static const size_t W1S_OFF  = 17159168;     // bf16 [256][512] BN-folded
// end = 17421312

__device__ __forceinline__ u16 f2bf(float f) {
  u32 u = __builtin_bit_cast(u32, f);
  u += 0x7FFFu + ((u >> 16) & 1u);     // RNE
  return (u16)(u >> 16);
}
__device__ __forceinline__ float bf2f(u16 h) {
  u32 u = ((u32)h) << 16;
  return __builtin_bit_cast(float, u);
}

// ---------------- K0: convert weights to bf16 ----------------
__global__ void k0_convert(const float* __restrict__ We,  const float* __restrict__ Wk1,
                           const float* __restrict__ Wk2, const float* __restrict__ Wv,
                           const float* __restrict__ W2,
                           u16* __restrict__ wEmb, u16* __restrict__ wV, u16* __restrict__ wW2)
{
  int i = blockIdx.x * 256 + threadIdx.x;
  if (i < 24576) {                          // padded embeds [agent][h][32]
    int which = i >> 13, rem = i & 8191, h = rem >> 5, c = rem & 31;
    const float* W = (which == 0) ? We : (which == 1) ? Wk1 : Wk2;
    wEmb[i] = (c < 13) ? f2bf(W[h*13 + c]) : (u16)0;
  } else if (i < 24576 + 65536) {           // Wv
    int j = i - 24576;
    wV[j] = f2bf(Wv[j]);
  } else if (i < 24576 + 65536 + 32768) {   // W2
    int j = i - 90112;
    wW2[j] = f2bf(W2[j]);
  }
}

// ---------------- K0b: fold Wu[i][j] = sum_h Wk[h][i] * Wq[h][j] ----------------
// then u = Wu @ e_q gives scores s_j = u . e_kj  (== Q . K_j)
__global__ void k0b_score_fold(const float* __restrict__ Wq, const float* __restrict__ Wk,
                               u16* __restrict__ Wu)
{
  int i = blockIdx.x, j = threadIdx.x;
  float acc = 0.f;
  #pragma unroll 4
  for (int h = 0; h < 256; ++h)
    acc += Wk[h*256 + i] * Wq[h*256 + j];
  Wu[i*256 + j] = f2bf(acc);
}

// ----- helpers: xbuf is [128 rows][1024 B], XOR-swizzled by (row&7)<<4 -----
// All tile-phase LDS traffic touches only the wave's OWN rows (cl = wv*16+lr),
// so no __syncthreads() inside attn_tile — compiler waitcnts order within-wave.
template<int NKS>
__device__ __forceinline__ void load_bfrags(const u8* __restrict__ xbuf, int cl, int colbase,
                                            int hi, s16x8* bk)
{
  #pragma unroll
  for (int ks = 0; ks < NKS; ++ks)
    bk[ks] = *(const s16x8*)(xbuf + ((cl*1024 + colbase + ks*64 + hi*16) ^ ((cl & 7) << 4)));
}

template<int NKS, int NM>
__device__ __forceinline__ void wgemmS(const u16* __restrict__ W, int rstride, int coff,
                                       const s16x8* bk, int lr, int hi, f32x4* acc)
{
  #pragma unroll
  for (int ks = 0; ks < NKS; ++ks) {
    #pragma unroll
    for (int m = 0; m < NM; ++m) {
      const s16x8 a = *(const s16x8*)(W + (m*16 + lr)*rstride + coff + ks*32 + hi*8);
      acc[m] = __builtin_amdgcn_mfma_f32_16x16x32_bf16(a, bk[ks], acc[m], 0, 0, 0);
    }
  }
}

// embed GEMM (K=32 padded), streamed per-m store into xbuf half (bias added)
__device__ __forceinline__ void egemm_store(const u16* __restrict__ Wj, s16x8 b,
                                            const float* __restrict__ bias,
                                            u8* __restrict__ xbuf, int colbase,
                                            int cl, int lr, int hi)
{
  #pragma unroll
  for (int m = 0; m < 16; ++m) {
    const s16x8 a = *(const s16x8*)(Wj + (m*16 + lr)*32 + hi*8);
    f32x4 k4 = {0.f, 0.f, 0.f, 0.f};
    k4 = __builtin_amdgcn_mfma_f32_16x16x32_bf16(a, b, k4, 0, 0, 0);
    f32x4 bb = ((const f32x4*)bias)[m*4 + hi];
    s16x4 p;
    #pragma unroll
    for (int r = 0; r < 4; ++r) p[r] = (short)f2bf(k4[r] + bb[r]);
    *(s16x4*)(xbuf + ((cl*1024 + colbase + m*32 + hi*8) ^ ((cl & 7) << 4))) = p;
  }
}

// score dot: s = sum_feat u[feat] * e_k[feat][cl]; lane holds feats m*16+4*hi+r
__device__ __forceinline__ float sdot(const u8* __restrict__ xbuf, const f32x4* u,
                                      int cl, int hi)
{
  float sp = 0.f;
  #pragma unroll
  for (int m = 0; m < 16; ++m) {
    const s16x4 v = *(const s16x4*)(xbuf + ((cl*1024 + 512 + m*32 + hi*8) ^ ((cl & 7) << 4)));
    #pragma unroll
    for (int r = 0; r < 4; ++r) sp += u[m][r] * bf2f((u16)v[r]);
  }
  sp += __shfl_xor(sp, 16);
  sp += __shfl_xor(sp, 32);
  return sp;
}

template<bool HASB, bool RELU, int NM>
__device__ __forceinline__ void store_half(u8* __restrict__ xbuf, int colbase, const f32x4* acc,
                                           const float* __restrict__ bias, int cl, int hi)
{
  #pragma unroll
  for (int m = 0; m < NM; ++m) {
    f32x4 bb = {0.f, 0.f, 0.f, 0.f};
    if (HASB) bb = ((const f32x4*)bias)[m*4 + hi];
    s16x4 p;
    #pragma unroll
    for (int r = 0; r < 4; ++r) {
      float v = acc[m][r] + bb[r];
      if (RELU) v = (v > 0.f) ? v : 0.f;
      p[r] = (short)f2bf(v);
    }
    *(s16x4*)(xbuf + ((cl*1024 + colbase + m*32 + hi*8) ^ ((cl & 7) << 4))) = p;
  }
}

// ---- attention tile: fills xbuf rows [e_q | atten] (bf16, swizzled), barrier-free ----
__device__ __forceinline__ void attn_tile(
    const float* __restrict__ x, int rowbase,
    const u16* __restrict__ wEmb, const float* __restrict__ be,
    const float* __restrict__ bk1, const float* __restrict__ bk2,
    const u16* __restrict__ wU, const u16* __restrict__ wV,
    const float* __restrict__ bv,
    u8* __restrict__ xbuf, int cl, int lr, int hi)
{
  const f32x4 zero4 = {0.f, 0.f, 0.f, 0.f};

  // per-lane embed B-frags (K padded to 32; lane covers k = hi*8..hi*8+7)
  s16x8 bfr[3];
  {
    const float* xr = x + (size_t)(rowbase + cl)*39;
    #pragma unroll
    for (int a = 0; a < 3; ++a) {
      s16x8 v = {0,0,0,0,0,0,0,0};
      if (hi == 0) {
        #pragma unroll
        for (int e = 0; e < 8; ++e) v[e] = (short)f2bf(xr[12*a + e]);
      } else if (hi == 1) {
        #pragma unroll
        for (int e = 0; e < 4; ++e) v[e] = (short)f2bf(xr[12*a + 8 + e]);
        v[4] = (short)f2bf(xr[36 + a]);   // action column -> padded slot 12
      }
      bfr[a] = v;
    }
  }

  // e_q -> bytes 0..511
  egemm_store(wEmb, bfr[0], be, xbuf, 0, cl, lr, hi);

  // u = Wu @ e_q  (scores via folded weight); e_k1 -> bytes 512..1023
  f32x4 uacc[16];
  #pragma unroll
  for (int m = 0; m < 16; ++m) uacc[m] = zero4;
  {
    s16x8 bk[8];
    load_bfrags<8>(xbuf, cl, 0, hi, bk);
    wgemmS<8, 16>(wU, 256, 0, bk, lr, hi, uacc);
  }
  egemm_store(wEmb + 8192, bfr[1], bk1, xbuf, 512, cl, lr, hi);

  float s1 = sdot(xbuf, uacc, cl, hi);

  // e_k2 -> bytes 512..1023 ; s2 ; softmax
  egemm_store(wEmb + 16384, bfr[2], bk2, xbuf, 512, cl, lr, hi);
  float s2 = sdot(xbuf, uacc, cl, hi);
  float w1 = 1.f / (1.f + __expf((s2 - s1) * 0.0625f));   // /sqrt(256)
  float w2 = 1.f - w1;

  // V2 from e_k2 (in LDS): vacc = w2 * leaky(V2 + bv)
  f32x4 vacc[16];
  #pragma unroll
  for (int m = 0; m < 16; ++m) vacc[m] = zero4;
  {
    s16x8 bk[8];
    load_bfrags<8>(xbuf, cl, 512, hi, bk);
    wgemmS<8, 16>(wV, 256, 0, bk, lr, hi, vacc);
  }
  #pragma unroll
  for (int m = 0; m < 16; ++m) {
    f32x4 bb = ((const f32x4*)bv)[m*4 + hi];
    #pragma unroll
    for (int r = 0; r < 4; ++r) {
      float v = vacc[m][r] + bb[r];
      v = (v > 0.f) ? v : 0.01f*v;
      vacc[m][r] = w2 * v;
    }
  }

  // recompute e_k1 -> bytes 512..1023 ; V1 ; combine
  egemm_store(wEmb + 8192, bfr[1], bk1, xbuf, 512, cl, lr, hi);
  {
    f32x4 vr[16];
    #pragma unroll
    for (int m = 0; m < 16; ++m) vr[m] = zero4;
    s16x8 bk[8];
    load_bfrags<8>(xbuf, cl, 512, hi, bk);
    wgemmS<8, 16>(wV, 256, 0, bk, lr, hi, vr);
    #pragma unroll
    for (int m = 0; m < 16; ++m) {
      f32x4 bb = ((const f32x4*)bv)[m*4 + hi];
      #pragma unroll
      for (int r = 0; r < 4; ++r) {
        float v = vr[m][r] + bb[r];
        v = (v > 0.f) ? v : 0.01f*v;
        vacc[m][r] += w1 * v;
      }
    }
  }

  // atten -> bytes 512..1023
  store_half<false, false, 16>(xbuf, 512, vacc, nullptr, cl, hi);
}

// ---------------- K1: attention pass -> BN partial sums ----------------
__global__ __launch_bounds__(512, 1) void k1_attn(
    const float* __restrict__ x,
    const u16* __restrict__ wEmb, const float* __restrict__ be,
    const float* __restrict__ bk1, const float* __restrict__ bk2,
    const u16* __restrict__ wU, const u16* __restrict__ wV,
    const float* __restrict__ bv,
    float* __restrict__ pA, float* __restrict__ pB)
{
  __shared__ __align__(16) u8 xbuf[131072];
  const int t = threadIdx.x;
  const int wg = blockIdx.x;
  const int rowbase = wg * 128;
  const int lane = t & 63;
  const int wv_ = t >> 6;
  const int lr = lane & 15, hi = lane >> 4;
  const int cl = wv_*16 + lr;

  attn_tile(x, rowbase, wEmb, be, bk1, bk2, wU, wV, bv, xbuf, cl, lr, hi);
  __syncthreads();   // cross-row consumer below

  // BN partials: thread handles feature pair (2fp, 2fp+1), row half rh
  const int fp = t & 255, rh = t >> 8;
  float s0 = 0.f, q0 = 0.f, s1 = 0.f, q1 = 0.f;
  for (int rr = 0; rr < 64; ++rr) {
    int r = rh*64 + rr;
    u32 v = *(const u32*)(xbuf + ((r*1024 + fp*4) ^ ((r & 7) << 4)));
    float a = bf2f((u16)(v & 0xFFFFu));
    float b = bf2f((u16)(v >> 16));
    s0 += a; q0 += a*a; s1 += b; q1 += b*b;
  }
  pA[(size_t)(2*fp)  *4096 + wg*2 + rh] = s0;
  pB[(size_t)(2*fp)  *4096 + wg*2 + rh] = q0;
  pA[(size_t)(2*fp+1)*4096 + wg*2 + rh] = s1;
  pB[(size_t)(2*fp+1)*4096 + wg*2 + rh] = q1;
}

// ---------------- K2: reduce BN partials -> mu, rstd ----------------
__global__ void k2_stats(const float* __restrict__ pA, const float* __restrict__ pB,
                         float* __restrict__ mu, float* __restrict__ rstd)
{
  int f = blockIdx.x, t = threadIdx.x;   // 512 blocks x 256 threads
  float s = 0.f, q = 0.f;
  #pragma unroll
  for (int k = 0; k < 16; ++k) {
    s += pA[(size_t)f*4096 + k*256 + t];
    q += pB[(size_t)f*4096 + k*256 + t];
  }
  #pragma unroll
  for (int off = 1; off < 64; off <<= 1) {
    s += __shfl_xor(s, off);
    q += __shfl_xor(q, off);
  }
  __shared__ float ls[4], lq[4];
  if ((t & 63) == 0) { ls[t >> 6] = s; lq[t >> 6] = q; }
  __syncthreads();
  if (t == 0) {
    float S = ls[0]+ls[1]+ls[2]+ls[3];
    float Q = lq[0]+lq[1]+lq[2]+lq[3];
    float m = S * (1.f/262144.f);
    float v = Q * (1.f/262144.f) - m*m;   // biased variance
    mu[f] = m;
    rstd[f] = 1.f / sqrtf(v + 1e-5f);
  }
}

// ---------------- K2b: fold BN into W1 ----------------
__global__ void k2b_fold(const float* __restrict__ W1, const float* __restrict__ b1,
                         const float* __restrict__ mu, const float* __restrict__ rstd,
                         u16* __restrict__ W1s, float* __restrict__ b1eff)
{
  int o = blockIdx.x, t = threadIdx.x;   // 256 blocks x 256 threads
  float local = 0.f;
  #pragma unroll
  for (int k = 0; k < 2; ++k) {
    int f = t + k*256;
    float w = W1[o*512 + f];
    float r = rstd[f];
    W1s[o*512 + f] = f2bf(w * r);
    local += w * r * mu[f];
  }
  #pragma unroll
  for (int off = 1; off < 64; off <<= 1) local += __shfl_xor(local, off);
  __shared__ float ls[4];
  if ((t & 63) == 0) ls[t >> 6] = local;
  __syncthreads();
  if (t == 0) b1eff[o] = b1[o] - (ls[0]+ls[1]+ls[2]+ls[3]);
}

// ---------------- K3: attention recompute + MLP head ----------------
__global__ __launch_bounds__(512, 1) void k3_mlp(
    const float* __restrict__ x,
    const u16* __restrict__ wEmb, const float* __restrict__ be,
    const float* __restrict__ bk1, const float* __restrict__ bk2,
    const u16* __restrict__ wU, const u16* __restrict__ wV,
    const float* __restrict__ bv,
    const u16* __restrict__ W1s, const float* __restrict__ b1eff,
    const u16* __restrict__ wW2, const float* __restrict__ b2,
    const float* __restrict__ W3, const float* __restrict__ b3,
    float* __restrict__ out)
{
  __shared__ __align__(16) u8 xbuf[131072];
  const int t = threadIdx.x;
  const int wg = blockIdx.x;
  const int rowbase = wg * 128;
  const int lane = t & 63;
  const int wv_ = t >> 6;
  const int lr = lane & 15, hi = lane >> 4;
  const int cl = wv_*16 + lr;
  const f32x4 zero4 = {0.f, 0.f, 0.f, 0.f};

  attn_tile(x, rowbase, wEmb, be, bk1, bk2, wU, wV, bv, xbuf, cl, lr, hi);

  // GEMM1: h1 = relu(X @ W1s.T + b1eff), K=512, B-frags in 2 halves (own rows only)
  f32x4 acc[16];
  #pragma unroll
  for (int m = 0; m < 16; ++m) acc[m] = zero4;
  {
    s16x8 bk[8];
    load_bfrags<8>(xbuf, cl, 0, hi, bk);
    wgemmS<8, 16>(W1s, 512, 0, bk, lr, hi, acc);
    load_bfrags<8>(xbuf, cl, 512, hi, bk);
    wgemmS<8, 16>(W1s, 512, 256, bk, lr, hi, acc);
  }
  store_half<true, true, 16>(xbuf, 0, acc, b1eff, cl, hi);   // h1 -> bytes 0..511

  // GEMM2: h2 = relu(h1 @ W2.T + b2), K=256 (own rows only)
  f32x4 acc2[8];
  #pragma unroll
  for (int m = 0; m < 8; ++m) acc2[m] = zero4;
  {
    s16x8 bk[8];
    load_bfrags<8>(xbuf, cl, 0, hi, bk);
    wgemmS<8, 8>(wW2, 256, 0, bk, lr, hi, acc2);
  }
  store_half<true, true, 8>(xbuf, 512, acc2, b2, cl, hi);    // h2 -> bytes 512..767
  __syncthreads();   // cross-row consumer below

  // out = h2 @ W3.T + b3 (one thread per row)
  if (t < 128) {
    float s = b3[0];
    #pragma unroll
    for (int jj = 0; jj < 16; ++jj) {
      const u32* v = (const u32*)(xbuf + ((t*1024 + 512 + jj*16) ^ ((t & 7) << 4)));
      #pragma unroll
      for (int q2 = 0; q2 < 4; ++q2) {
        u32 u = v[q2];
        s += bf2f((u16)(u & 0xFFFFu)) * W3[jj*8 + q2*2];
        s += bf2f((u16)(u >> 16))     * W3[jj*8 + q2*2 + 1];
      }
    }
    out[rowbase + t] = s;
  }
}

extern "C" void kernel_launch(void* const* d_in, const int* in_sizes, int n_in,
                              void* d_out, int out_size, void* d_ws, size_t ws_size,
                              hipStream_t stream)
{
  const float* x   = (const float*)d_in[0];
  const float* We  = (const float*)d_in[1];
  const float* be  = (const float*)d_in[2];
  const float* Wk1 = (const float*)d_in[3];
  const float* bk1 = (const float*)d_in[4];
  const float* Wk2 = (const float*)d_in[5];
  const float* bk2 = (const float*)d_in[6];
  const float* Wq  = (const float*)d_in[7];
  const float* Wk  = (const float*)d_in[8];
  const float* Wv  = (const float*)d_in[9];
  const float* bv  = (const float*)d_in[10];
  const float* W1  = (const float*)d_in[11];
  const float* b1  = (const float*)d_in[12];
  const float* W2  = (const float*)d_in[13];
  const float* b2  = (const float*)d_in[14];
  const float* W3  = (const float*)d_in[15];
  const float* b3  = (const float*)d_in[16];

  u8* ws = (u8*)d_ws;
  float* pA    = (float*)(ws + PA_OFF);
  float* pB    = (float*)(ws + PB_OFF);
  float* mu    = (float*)(ws + MU_OFF);
  float* rstd  = (float*)(ws + RSTD_OFF);
  float* b1eff = (float*)(ws + B1E_OFF);
  u16*   wEmb  = (u16*)(ws + WEMB_OFF);
  u16*   wU    = (u16*)(ws + WU_OFF);
  u16*   wVb   = (u16*)(ws + WV_OFF);
  u16*   wW2   = (u16*)(ws + W2_OFF);
  u16*   wW1s  = (u16*)(ws + W1S_OFF);

  k0_convert<<<dim3(480), dim3(256), 0, stream>>>(We, Wk1, Wk2, Wv, W2, wEmb, wVb, wW2);
  k0b_score_fold<<<dim3(256), dim3(256), 0, stream>>>(Wq, Wk, wU);
  k1_attn<<<dim3(NWG), dim3(512), 0, stream>>>(x, wEmb, be, bk1, bk2, wU, wVb, bv, pA, pB);
  k2_stats<<<dim3(512), dim3(256), 0, stream>>>(pA, pB, mu, rstd);
  k2b_fold<<<dim3(256), dim3(256), 0, stream>>>(W1, b1, mu, rstd, wW1s, b1eff);
  k3_mlp<<<dim3(NWG), dim3(512), 0, stream>>>(x, wEmb, be, bk1, bk2, wU, wVb, bv,
                                              wW1s, b1eff, wW2, b2, W3, b3,
                                              (float*)d_out);
}